// Round 6
// baseline (123.541 us; speedup 1.0000x reference)
//
#include <hip/hip_runtime.h>
#include <math.h>

// NGRU via MFMA, R6 = R4 structure with the spill bug fixed.
// Only layer 1 of the 2 parallel GRU layers contributes (reference returns
// h_final[-1]); layer 0 is skipped.
//
// Shapes: x (64,48,256,64) f32; Wih/Whh (2,192,64); bih/bhh (2,192).
// rows = B*N = 16384 independent GRU sequences, T=48, H=64.
//
// Structure: 1024 blocks x 256 threads (4 waves), 16 rows/block.
// __launch_bounds__(256,2): R4 proved (256,4) forces a 128-VGPR cap that
// spills the 96-VGPR B-fragment set (VGPR_Count 64, 128MB scratch traffic).
// At the natural ~116 VGPRs the HW occupancy is 4 waves/SIMD anyway
// (halving points 64/128/256) -> 4 blocks/CU = 4 independent barrier
// domains, 16 waves/CU, LDS 4 x 17.5 KB = 70 KB.
//
// Wave nw owns output columns j in [16nw,16nw+16) for ALL FOUR gates
// (g=0:r, 1:z, 2:gin, 3:ghn) -> gate epilogue fully register-local.
// Zero B-tiles skipped: 12 kt-slots, 36 MFMA/wave/step.
//
// A = [x_t | h_{t-1}] bf16 hi/lo planes, ping-ponged -> ONE barrier/step.
// Lo-plane stagger +16 shorts == +8 banks (PLANE = 16*136+16), so paired
// h dword writes (even lane -> hi plane, odd lane -> lo plane) cover all
// 32 banks 2-way = free. f32->bf16 via v_cvt_pk_bf16_f32 (RNE,
// bit-identical to scalar path; R4/R5-verified).
//
// Split-bf16: v = hi + lo; product = AhBh + AhBl + AlBh (~2^-17 rel), same
// accumulation order as R3/R4/R5 -> bit-identical numerics.

#define TT 48
#define HH 64
#define GG 192
#define NN 256
#define RPB 16          // rows per block
#define NTHREADS 256    // 4 waves
#define AK 136          // A row stride in shorts (128 + 8 pad)
#define PLANE 2192      // shorts per plane (16*136 + 16 stagger = +8 banks)
#define ABUF (2*PLANE)  // shorts per A buffer (hi+lo)

typedef __attribute__((ext_vector_type(8))) short bs8;     // 8 bf16
typedef __attribute__((ext_vector_type(4))) float f32x4;   // MFMA accum

__device__ __forceinline__ float sigm(float v) {
    return __builtin_amdgcn_rcpf(1.f + __expf(-v));
}
__device__ __forceinline__ float tanh_f(float v) {
    float a = fabsf(v);
    float e = __expf(2.f * a);
    float t = 1.f - 2.f * __builtin_amdgcn_rcpf(e + 1.f);
    return v < 0.f ? -t : t;
}
// packed f32x2 -> bf16x2 (RNE): D[15:0]=bf16(S0), D[31:16]=bf16(S1)
__device__ __forceinline__ unsigned cvtpk(float lo, float hi) {
    unsigned r;
    asm("v_cvt_pk_bf16_f32 %0, %1, %2" : "=v"(r) : "v"(lo), "v"(hi));
    return r;
}
__device__ __forceinline__ float ubits(unsigned u) { return __uint_as_float(u); }
// scalar RNE helpers (B build only; one-time)
__device__ __forceinline__ unsigned short f2bf(float f) {
    unsigned u = __float_as_uint(f);
    return (unsigned short)((u + 0x7fffu + ((u >> 16) & 1u)) >> 16);
}
__device__ __forceinline__ float bf2f(unsigned short b) {
    return __uint_as_float(((unsigned)b) << 16);
}

__global__ __launch_bounds__(NTHREADS, 2)
void ngru_mfma6(const float* __restrict__ x,
                const float* __restrict__ Wih,
                const float* __restrict__ Whh,
                const float* __restrict__ bih,
                const float* __restrict__ bhh,
                float* __restrict__ out)
{
    extern __shared__ __align__(16) short lds_s[];   // 2 x ABUF shorts

    const int tid  = threadIdx.x;
    const int lane = tid & 63;
    const int nw   = tid >> 6;          // wave 0..3 -> j slice [16nw,16nw+16)
    const int c0   = lane & 15;         // C col within tile / A row index
    const int rq   = lane >> 4;         // quarter-wave
    const int j    = nw * 16 + c0;
    const bool odd = (c0 & 1);

    const int grow0 = blockIdx.x * RPB;
    const int bb    = grow0 / NN;
    const int n0    = grow0 % NN;

    const float* Wi = Wih + GG * HH;    // layer 1
    const float* Wh = Whh + GG * HH;

    // ---- B fragments in registers: 12 kt-slots (zero tiles skipped) ----
    bs8 Bh[12], Bl[12];
    #pragma unroll
    for (int g = 0; g < 4; ++g) {
        const int ktlo = (g == 3) ? 2 : 0;
        const int kthi = (g == 2) ? 2 : 4;
        #pragma unroll
        for (int kt = ktlo; kt < kthi; ++kt) {
            const int slot = (g < 2) ? g * 4 + kt : 8 + (g - 2) * 2 + (kt & 1);
            const bool isWi = (kt < 2);
            const int gbase = (g >= 2) ? 2 : g;
            const float* src = (isWi ? Wi : Wh)
                             + (gbase * 64 + j) * HH + (kt & 1) * 32 + rq * 8;
            bs8 h8, l8;
            #pragma unroll
            for (int q = 0; q < 8; ++q) {
                float v = src[q];
                unsigned short hb = f2bf(v);
                unsigned short lb = f2bf(v - bf2f(hb));
                h8[q] = (short)hb; l8[q] = (short)lb;
            }
            Bh[slot] = h8; Bl[slot] = l8;
        }
    }

    // ---- biases (layer 1), r/z pre-summed; n biases stay separate ----
    const float brz  = bih[GG + j]      + bhh[GG + j];
    const float bzz  = bih[GG + 64 + j] + bhh[GG + 64 + j];
    const float bi_n = bih[GG + 128 + j];
    const float bh_n = bhh[GG + 128 + j];

    // ---- init buf0: zero h region, stage x_0 ----
    const int xrow = tid >> 4;          // 0..15
    const int xc   = (tid & 15) * 4;    // elem/short offset 0,4,...,60
    {
        // zero h region (both planes), 8B per thread per plane
        *(uint2*)(lds_s + xrow * AK + 64 + xc)         = (uint2){0u, 0u};
        *(uint2*)(lds_s + PLANE + xrow * AK + 64 + xc) = (uint2){0u, 0u};

        const float* xsrc = x + ((size_t)(bb * TT) * NN + n0 + xrow) * HH + xc;
        float4 p = *(const float4*)xsrc;
        unsigned h0 = cvtpk(p.x, p.y), h1 = cvtpk(p.z, p.w);
        float r0 = p.x - ubits(h0 << 16), r1 = p.y - ubits(h0 & 0xffff0000u);
        float r2 = p.z - ubits(h1 << 16), r3 = p.w - ubits(h1 & 0xffff0000u);
        unsigned l0 = cvtpk(r0, r1), l1 = cvtpk(r2, r3);
        *(uint2*)(lds_s + xrow * AK + xc)         = (uint2){h0, h1};
        *(uint2*)(lds_s + PLANE + xrow * AK + xc) = (uint2){l0, l1};
    }

    float hreg[4];
    #pragma unroll
    for (int r = 0; r < 4; ++r) hreg[r] = 0.f;

    __syncthreads();   // buf0 ready for t=0

    for (int t = 0; t < TT; ++t) {
        short* cur = lds_s + (t & 1) * ABUF;
        short* nxt = lds_s + ((t & 1) ^ 1) * ABUF;

        // prefetch x_{t+1} (HBM latency hides under MFMA + epilogue)
        float4 p;
        const bool hasNext = (t + 1 < TT);
        if (hasNext) {
            const float* xsrc =
                x + ((size_t)(bb * TT + t + 1) * NN + n0 + xrow) * HH + xc;
            p = *(const float4*)xsrc;
        }

        // ===== MFMA: 4 gate-tiles, kt-outer (A liveness = 8 regs) =====
        f32x4 acc[4];
        #pragma unroll
        for (int g = 0; g < 4; ++g) acc[g] = (f32x4){0.f, 0.f, 0.f, 0.f};

        const short* ab = cur + c0 * AK + rq * 8;
        __builtin_amdgcn_s_setprio(1);
        #pragma unroll
        for (int kt = 0; kt < 4; ++kt) {
            bs8 Ah = *(const bs8*)(ab + kt * 32);
            bs8 Al = *(const bs8*)(ab + PLANE + kt * 32);
            const int s0 = kt;                                    // gate r
            const int s1 = 4 + kt;                                // gate z
            const int s2 = (kt < 2) ? (8 + kt) : (10 + (kt & 1)); // gin/ghn
            const int g2 = (kt < 2) ? 2 : 3;
            acc[0] = __builtin_amdgcn_mfma_f32_16x16x32_bf16(Ah, Bh[s0], acc[0], 0, 0, 0);
            acc[0] = __builtin_amdgcn_mfma_f32_16x16x32_bf16(Ah, Bl[s0], acc[0], 0, 0, 0);
            acc[0] = __builtin_amdgcn_mfma_f32_16x16x32_bf16(Al, Bh[s0], acc[0], 0, 0, 0);
            acc[1] = __builtin_amdgcn_mfma_f32_16x16x32_bf16(Ah, Bh[s1], acc[1], 0, 0, 0);
            acc[1] = __builtin_amdgcn_mfma_f32_16x16x32_bf16(Ah, Bl[s1], acc[1], 0, 0, 0);
            acc[1] = __builtin_amdgcn_mfma_f32_16x16x32_bf16(Al, Bh[s1], acc[1], 0, 0, 0);
            acc[g2] = __builtin_amdgcn_mfma_f32_16x16x32_bf16(Ah, Bh[s2], acc[g2], 0, 0, 0);
            acc[g2] = __builtin_amdgcn_mfma_f32_16x16x32_bf16(Ah, Bl[s2], acc[g2], 0, 0, 0);
            acc[g2] = __builtin_amdgcn_mfma_f32_16x16x32_bf16(Al, Bh[s2], acc[g2], 0, 0, 0);
        }
        __builtin_amdgcn_s_setprio(0);

        // ===== epilogue: register-local gates; h -> nxt buffer =====
        short* hp = nxt + (odd ? PLANE : 0);
        #pragma unroll
        for (int r = 0; r < 4; ++r) {
            const int row = rq * 4 + r;
            float sr  = acc[0][r] + brz;
            float sz  = acc[1][r] + bzz;
            float gin = acc[2][r] + bi_n;
            float ghn = acc[3][r] + bh_n;
            float rg = sigm(sr);
            float zg = sigm(sz);
            float ng = tanh_f(fmaf(rg, ghn, gin));
            float hn = fmaf(zg, hreg[r] - ng, ng);   // (1-z)n + z h
            hreg[r] = hn;
            // paired dword write: even lane -> hi-plane dword {j, j+1},
            // odd lane -> lo-plane dword; planes staggered 8 banks -> 2-way
            float partner = __shfl_xor(hn, 1);
            float ve = odd ? partner : hn;     // value at even column
            float vo = odd ? hn : partner;     // value at odd column
            unsigned hd = cvtpk(ve, vo);
            float re = ve - ubits(hd << 16);
            float ro = vo - ubits(hd & 0xffff0000u);
            unsigned ld = cvtpk(re, ro);
            unsigned w = odd ? ld : hd;
            *(unsigned*)(hp + row * AK + 64 + (j & ~1)) = w;
        }

        if (hasNext) {
            unsigned h0 = cvtpk(p.x, p.y), h1 = cvtpk(p.z, p.w);
            float r0 = p.x - ubits(h0 << 16), r1 = p.y - ubits(h0 & 0xffff0000u);
            float r2 = p.z - ubits(h1 << 16), r3 = p.w - ubits(h1 & 0xffff0000u);
            unsigned l0 = cvtpk(r0, r1), l1 = cvtpk(r2, r3);
            *(uint2*)(nxt + xrow * AK + xc)         = (uint2){h0, h1};
            *(uint2*)(nxt + PLANE + xrow * AK + xc) = (uint2){l0, l1};
            __syncthreads();   // nxt (h_t + x_{t+1}) ready for step t+1
        }
    }

    #pragma unroll
    for (int r = 0; r < 4; ++r)
        out[(size_t)(grow0 + rq * 4 + r) * HH + j] = hreg[r];
}

extern "C" void kernel_launch(void* const* d_in, const int* in_sizes, int n_in,
                              void* d_out, int out_size, void* d_ws, size_t ws_size,
                              hipStream_t stream) {
    const float* x   = (const float*)d_in[0];
    const float* Wih = (const float*)d_in[1];
    const float* Whh = (const float*)d_in[2];
    const float* bih = (const float*)d_in[3];
    const float* bhh = (const float*)d_in[4];
    float* out = (float*)d_out;

    const int lds_bytes = 2 * ABUF * (int)sizeof(short);   // 17,536 B
    (void)hipFuncSetAttribute((const void*)ngru_mfma6,
                        hipFuncAttributeMaxDynamicSharedMemorySize, lds_bytes);

    dim3 grid(16384 / RPB);     // 1024 blocks, 4 per CU (VGPR-limited)
    dim3 block(NTHREADS);
    ngru_mfma6<<<grid, block, lds_bytes, stream>>>(x, Wih, Whh, bih, bhh, out);
}